// Round 6
// baseline (35.707 us; speedup 1.0000x reference)
//
#include <hip/hip_runtime.h>
#include <hip/hip_bf16.h>

#define HID   64
#define NHD   8
#define IT    2            // i's per block
#define WAVES 8
#define NFIX  1024         // problem N (out tile LDS dimension)

typedef _Float16 f16x8 __attribute__((ext_vector_type(8)));
typedef float    f32x4 __attribute__((ext_vector_type(4)));

// out[b,k,i,j] = sum_h relu( (u_j[h]+b1[h]) - u_i[h] ) * W2[h,k] + b2[k]
// Block owns (b, i0..i0+IT-1, ALL j, all k). Compute: fp16 MFMA pipeline
// (validated r5): aLo=W2^T rows0..7, aHi=rows8..15 -> D rows0..7=j-tile0,
// rows8..15=j-tile1; all 64 lanes useful. Results land in sOut[8][IT][N] (LDS).
// Epilogue: wave w streams plane w to global as IT*N contiguous floats
// (1KB/inst, 8KB sequential per wave) -- fixes the 128B-granule scatter that
// capped rounds 2-5 at ~2.8 TB/s effective write BW.
__global__ __launch_bounds__(WAVES * 64, 4) void relposenc_lds(
    const float* __restrict__ xyz, const float* __restrict__ W1,
    const float* __restrict__ b1,  const float* __restrict__ W2,
    const float* __restrict__ b2,  float* __restrict__ out, int N) {

  __shared__ float    sOut[NHD][IT][NFIX];   // 64 KB
  __shared__ _Float16 sU[IT][HID];

  const int tid  = threadIdx.x;
  const int wave = tid >> 6;
  const int lane = tid & 63;
  const int col  = lane & 15;
  const int hgrp = lane >> 4;
  const int b    = blockIdx.y;
  const int i0   = blockIdx.x * IT;

  const float* xb = xyz + (size_t)b * 3 * N;

  // ---- stage u_i (f16) for the block's IT i's ----
  if (tid < IT * HID) {
    int ii = tid >> 6, h = tid & 63;
    int i  = i0 + ii;
    float u = fmaf(xb[i], W1[h],
              fmaf(xb[N + i], W1[HID + h],
                   xb[2 * N + i] * W1[2 * HID + h]));
    sU[ii][h] = (_Float16)u;
  }

  // ---- W1/b1 fragments in registers (this lane's h-slices) ----
  f16x8 w1f[2][3], bbf[2];
  #pragma unroll
  for (int kb = 0; kb < 2; ++kb)
    #pragma unroll
    for (int e = 0; e < 8; ++e) {
      int h = kb * 32 + hgrp * 8 + e;
      w1f[kb][0][e] = (_Float16)W1[h];
      w1f[kb][1][e] = (_Float16)W1[HID + h];
      w1f[kb][2][e] = (_Float16)W1[2 * HID + h];
      bbf[kb][e]    = (_Float16)b1[h];
    }

  // ---- A fragments: W2^T in low rows (aLo) / high rows (aHi) ----
  f16x8 aLo[2], aHi[2];
  #pragma unroll
  for (int kb = 0; kb < 2; ++kb)
    #pragma unroll
    for (int e = 0; e < 8; ++e) {
      int h = kb * 32 + hgrp * 8 + e;
      aLo[kb][e] = (_Float16)((col < NHD)  ? W2[h * NHD + col]       : 0.f);
      aHi[kb][e] = (_Float16)((col >= NHD) ? W2[h * NHD + (col - 8)] : 0.f);
    }
  const int kbase = (hgrp & 1) << 2;
  float b2v[4];
  #pragma unroll
  for (int r = 0; r < 4; ++r) b2v[r] = b2[kbase + r];

  __syncthreads();

  // ---- u fragments for both i's (reused across all j-groups) ----
  f16x8 uf[IT][2];
  #pragma unroll
  for (int ii = 0; ii < IT; ++ii)
    #pragma unroll
    for (int kb = 0; kb < 2; ++kb)
      uf[ii][kb] = *(const f16x8*)&sU[ii][kb * 32 + hgrp * 8];

  const int jloc   = col + ((lane >> 5) << 4);   // 0..31 within j-group
  const int ngroup = N / (WAVES * 32);           // j-groups per wave
  const f16x8 z = {0, 0, 0, 0, 0, 0, 0, 0};

  for (int g = 0; g < ngroup; ++g) {
    const int jbase = (wave * ngroup + g) * 32;

    // aj = u_j + b1 (packed f16) for this group's 2 j-tiles
    f16x8 aj[2][2];
    #pragma unroll
    for (int t = 0; t < 2; ++t) {
      int j = jbase + t * 16 + col;
      f16x8 x0 = (_Float16)xb[j];
      f16x8 x1 = (_Float16)xb[N + j];
      f16x8 x2 = (_Float16)xb[2 * N + j];
      #pragma unroll
      for (int kb = 0; kb < 2; ++kb)
        aj[t][kb] = __builtin_elementwise_fma(x0, w1f[kb][0],
                    __builtin_elementwise_fma(x1, w1f[kb][1],
                    __builtin_elementwise_fma(x2, w1f[kb][2], bbf[kb])));
    }

    #pragma unroll
    for (int ii = 0; ii < IT; ++ii) {
      f16x8 d00 = __builtin_elementwise_max(aj[0][0] - uf[ii][0], z);
      f16x8 d01 = __builtin_elementwise_max(aj[0][1] - uf[ii][1], z);
      f16x8 d10 = __builtin_elementwise_max(aj[1][0] - uf[ii][0], z);
      f16x8 d11 = __builtin_elementwise_max(aj[1][1] - uf[ii][1], z);

      f32x4 cA = {b2v[0], b2v[1], b2v[2], b2v[3]};   // fold b2 into acc init
      f32x4 cB = {0.f, 0.f, 0.f, 0.f};
      cA = __builtin_amdgcn_mfma_f32_16x16x32_f16(aLo[0], d00, cA, 0, 0, 0);
      cA = __builtin_amdgcn_mfma_f32_16x16x32_f16(aLo[1], d01, cA, 0, 0, 0);
      cB = __builtin_amdgcn_mfma_f32_16x16x32_f16(aHi[0], d10, cB, 0, 0, 0);
      cB = __builtin_amdgcn_mfma_f32_16x16x32_f16(aHi[1], d11, cB, 0, 0, 0);

      const int jj = jbase + jloc;
      #pragma unroll
      for (int r = 0; r < 4; ++r)
        sOut[kbase + r][ii][jj] = cA[r] + cB[r];
    }
  }

  __syncthreads();

  // ---- epilogue: wave w streams plane k=w (IT*N contiguous floats) ----
  {
    const float* src = &sOut[wave][0][0];
    float* dst = out + (((size_t)(b * NHD + wave)) * N + i0) * N;
    const int total = IT * N;                     // 2048 floats
    #pragma unroll
    for (int it = 0; it < total / 256; ++it) {    // 256 floats per wave-inst
      int off = it * 256 + lane * 4;
      f32x4 v = *(const f32x4*)(src + off);
      *(f32x4*)(dst + off) = v;
    }
  }
}

extern "C" void kernel_launch(void* const* d_in, const int* in_sizes, int n_in,
                              void* d_out, int out_size, void* d_ws, size_t ws_size,
                              hipStream_t stream) {
  const float* xyz = (const float*)d_in[0];
  const float* W1  = (const float*)d_in[1];
  const float* b1  = (const float*)d_in[2];
  const float* W2  = (const float*)d_in[3];
  const float* b2  = (const float*)d_in[4];
  float* out = (float*)d_out;

  const long long in0 = in_sizes[0];
  const int N = (int)((3LL * (long long)out_size) / (8LL * in0));
  const int B = (int)(in0 / (3LL * N));

  dim3 grid(N / IT, B);
  relposenc_lds<<<grid, WAVES * 64, 0, stream>>>(xyz, W1, b1, W2, b2, out, N);
}

// Round 7
// 27.878 us; speedup vs baseline: 1.2809x; 1.2809x over previous
//
#include <hip/hip_runtime.h>

#define HID   64
#define NHD   8
#define IT    4            // i's per block
#define WAVES 4            // 256 threads per block
#define JW    128          // j's per wave (4 MFMA tile-pairs of 32)
#define JBLK  (WAVES*JW)   // 512 j's per block

typedef _Float16 f16x8 __attribute__((ext_vector_type(8)));
typedef float    f32x4 __attribute__((ext_vector_type(4)));

// out[b,k,i,j] = sum_h relu( (u_j[h]+b1[h]) - u_i[h] ) * W2[h,k] + b2[k]
// fp16 MFMA pipeline (validated r5/r6): aLo = W2^T rows 0..7, aHi = rows 8..15
// -> D rows 0..7 = lo j-tile, rows 8..15 = hi j-tile; all 64 lanes store useful
// data. NEW: each wave owns a 128-j window (4 tile-pairs) and accumulates all 4
// pairs in registers before storing r-major, so each (k-plane, i) visit writes
// 4 adjacent 128B segments = 512B contiguous, issued in address order --
// attacking the DRAM row-buffer locality that capped r2-r5 at ~2.8 TB/s.
__global__ __launch_bounds__(WAVES * 64) void relposenc_jwide(
    const float* __restrict__ xyz, const float* __restrict__ W1,
    const float* __restrict__ b1,  const float* __restrict__ W2,
    const float* __restrict__ b2,  float* __restrict__ out, int N) {

  __shared__ _Float16 sU[IT][HID];

  const int tid  = threadIdx.x;
  const int wave = tid >> 6;
  const int lane = tid & 63;
  const int col  = lane & 15;
  const int hgrp = lane >> 4;
  const int b    = blockIdx.z;
  const int i0   = blockIdx.y * IT;
  const int jwb  = blockIdx.x * JBLK + wave * JW;   // wave's j-window base

  const float* xb = xyz + (size_t)b * 3 * N;

  // ---- stage u_i (f16) for the block's IT i's (IT*HID == blockDim) ----
  {
    int ii = tid >> 6, h = tid & 63;
    int i  = i0 + ii;
    float u = fmaf(xb[i], W1[h],
              fmaf(xb[N + i], W1[HID + h],
                   xb[2 * N + i] * W1[2 * HID + h]));
    sU[ii][h] = (_Float16)u;
  }

  // ---- W1/b1 fragments (this lane's h-slices) for the aj build ----
  f16x8 w1f[2][3], bbf[2];
  #pragma unroll
  for (int kb = 0; kb < 2; ++kb)
    #pragma unroll
    for (int e = 0; e < 8; ++e) {
      int h = kb * 32 + hgrp * 8 + e;
      w1f[kb][0][e] = (_Float16)W1[h];
      w1f[kb][1][e] = (_Float16)W1[HID + h];
      w1f[kb][2][e] = (_Float16)W1[2 * HID + h];
      bbf[kb][e]    = (_Float16)b1[h];
    }

  // ---- A fragments: W2^T in low rows (aLo) / high rows (aHi) ----
  f16x8 aLo[2], aHi[2];
  #pragma unroll
  for (int kb = 0; kb < 2; ++kb)
    #pragma unroll
    for (int e = 0; e < 8; ++e) {
      int h = kb * 32 + hgrp * 8 + e;
      aLo[kb][e] = (_Float16)((col < NHD)  ? W2[h * NHD + col]       : 0.f);
      aHi[kb][e] = (_Float16)((col >= NHD) ? W2[h * NHD + (col - 8)] : 0.f);
    }
  const int kbase = (hgrp & 1) << 2;
  float b2v[4];
  #pragma unroll
  for (int r = 0; r < 4; ++r) b2v[r] = b2[kbase + r];

  // ---- aj = u_j + b1 (f16) for the whole 128-j window: 4 pairs x 2 tiles ----
  f16x8 aj[4][2][2];
  #pragma unroll
  for (int p = 0; p < 4; ++p)
    #pragma unroll
    for (int t = 0; t < 2; ++t) {
      int j = jwb + (p * 2 + t) * 16 + col;
      f16x8 x0 = (_Float16)xb[j];
      f16x8 x1 = (_Float16)xb[N + j];
      f16x8 x2 = (_Float16)xb[2 * N + j];
      #pragma unroll
      for (int kb = 0; kb < 2; ++kb)
        aj[p][t][kb] = __builtin_elementwise_fma(x0, w1f[kb][0],
                       __builtin_elementwise_fma(x1, w1f[kb][1],
                       __builtin_elementwise_fma(x2, w1f[kb][2], bbf[kb])));
    }

  __syncthreads();

  // store geometry: lanes 0-31 -> lo tile, 32-63 -> hi tile (validated)
  const int jloc = col + ((lane >> 5) << 4);
  size_t rowbase[4];
  #pragma unroll
  for (int r = 0; r < 4; ++r)
    rowbase[r] = (((size_t)(b * NHD + kbase + r) * N + i0) * N) + jwb + jloc;

  const f16x8 z = {0, 0, 0, 0, 0, 0, 0, 0};

  for (int ii = 0; ii < IT; ++ii) {
    f16x8 u0 = *(const f16x8*)&sU[ii][hgrp * 8];
    f16x8 u1 = *(const f16x8*)&sU[ii][32 + hgrp * 8];

    f32x4 cA[4], cB[4];
    #pragma unroll
    for (int p = 0; p < 4; ++p) {
      f16x8 d00 = __builtin_elementwise_max(aj[p][0][0] - u0, z);
      f16x8 d01 = __builtin_elementwise_max(aj[p][0][1] - u1, z);
      f16x8 d10 = __builtin_elementwise_max(aj[p][1][0] - u0, z);
      f16x8 d11 = __builtin_elementwise_max(aj[p][1][1] - u1, z);

      cA[p] = (f32x4){b2v[0], b2v[1], b2v[2], b2v[3]};  // fold b2 into acc
      cB[p] = (f32x4){0.f, 0.f, 0.f, 0.f};
      cA[p] = __builtin_amdgcn_mfma_f32_16x16x32_f16(aLo[0], d00, cA[p], 0, 0, 0);
      cA[p] = __builtin_amdgcn_mfma_f32_16x16x32_f16(aLo[1], d01, cA[p], 0, 0, 0);
      cB[p] = __builtin_amdgcn_mfma_f32_16x16x32_f16(aHi[0], d10, cB[p], 0, 0, 0);
      cB[p] = __builtin_amdgcn_mfma_f32_16x16x32_f16(aHi[1], d11, cB[p], 0, 0, 0);
    }

    // r-major store: per k-plane, 4 adjacent 128B segments in address order
    const size_t ioff = (size_t)ii * N;
    #pragma unroll
    for (int r = 0; r < 4; ++r)
      #pragma unroll
      for (int p = 0; p < 4; ++p)
        out[rowbase[r] + ioff + p * 32] = cA[p][r] + cB[p][r];
  }
}

extern "C" void kernel_launch(void* const* d_in, const int* in_sizes, int n_in,
                              void* d_out, int out_size, void* d_ws, size_t ws_size,
                              hipStream_t stream) {
  const float* xyz = (const float*)d_in[0];
  const float* W1  = (const float*)d_in[1];
  const float* b1  = (const float*)d_in[2];
  const float* W2  = (const float*)d_in[3];
  const float* b2  = (const float*)d_in[4];
  float* out = (float*)d_out;

  const long long in0 = in_sizes[0];
  const int N = (int)((3LL * (long long)out_size) / (8LL * in0));
  const int B = (int)(in0 / (3LL * N));

  dim3 grid(N / JBLK, N / IT, B);
  relposenc_jwide<<<grid, WAVES * 64, 0, stream>>>(xyz, W1, b1, W2, b2, out, N);
}